// Round 12
// baseline (191.322 us; speedup 1.0000x reference)
//
#include <hip/hip_runtime.h>

#define BSZ 8
#define TLEN 2048
#define CDIM 768
#define LCH 16
#define NCH (TLEN / LCH)

typedef __attribute__((ext_vector_type(4))) float f32x4;
typedef __attribute__((ext_vector_type(8))) _Float16 f16x8;   // 8 f16 = 4 VGPRs (MFMA operand)
typedef __attribute__((ext_vector_type(4))) _Float16 f16x4;
typedef __attribute__((ext_vector_type(4))) float float4v;

// async global->LDS, 16B per lane; LDS dest = wave-uniform base + lane*16
#define GLD16(g, l)                                                          \
    __builtin_amdgcn_global_load_lds(                                        \
        (const __attribute__((address_space(1))) unsigned int*)(g),          \
        (__attribute__((address_space(3))) unsigned int*)(l), 16, 0, 0)

// ---------------------------------------------------------------------------
// f32 -> f16 cast, 4 elements/thread (x and weight planes)
// ---------------------------------------------------------------------------
__global__ __launch_bounds__(256) void split_f16(const float* __restrict__ src,
                                                 _Float16* __restrict__ dst, int n4) {
    int i = blockIdx.x * 256 + threadIdx.x;
    if (i >= n4) return;
    float4v f = ((const float4v*)src)[i];
    f16x4 h;
    #pragma unroll
    for (int j = 0; j < 4; ++j) h[j] = (_Float16)f[j];
    ((f16x4*)dst)[i] = h;
}

// ---------------------------------------------------------------------------
// 4-phase/K-tile counted-vmcnt fp16 GEMM (NT): out[m,n] = sum_k A[m,k]*W[n,k].
// BM=BN=256, BK=64, 512 thr = 8 waves (2M x 4N), per-wave output 128x64.
// K-HALF sections (all 256 rows x 32K = 16KB, 64B rows): staged per phase in
// order {A ks0, B ks0, A ks1, B ks1} for tile t+1 while computing tile t.
// Phase p of tile t: ks=p>>1, mh=p&1:
//   { ds_read A frags mh*4..mh*4+3 (ks) [+ B frags at mh==0]
//     | stage section p of tile t+1 (2 GLD16/thread)
//     -> barrier -> lgkmcnt(0)+sched_barrier -> setprio(1)
//     -> 16 MFMA -> setprio(0) -> vmcnt(4) [last tile: vmcnt(0)] -> barrier }
// Every read targets a section staged >=3 phases earlier; vmcnt(4) keeps the
// 2 newest stages in flight (T4 counted, never drain-to-0 mid-loop).
// 64B section rows => stride-64 ds_read_b128 is bank-conflict-floor, NO
// swizzle needed; staging addresses fully linear.
// LDS: 2 bufs x 64KB. W concatenated [NTL*256 x 768]; merged NTL=9: nt/3 ->
// kh|vh|srh (sigmoid on srh); Wo NTL=3: f32 store.
// Block decode: bid = xcd + 8*(mt*NTL + nt); m0 = (xcd*mpx + mt)*256.
// ---------------------------------------------------------------------------
__global__ __launch_bounds__(512, 2) void gemm_8ph(
    const _Float16* __restrict__ A, const _Float16* __restrict__ W,
    _Float16* __restrict__ o0, _Float16* __restrict__ o1, _Float16* __restrict__ o2,
    float* __restrict__ of32, int mpx, int NTL) {
    constexpr int K = CDIM;          // 768
    constexpr int NT = K / 64;       // 12 K-tiles
    __shared__ __align__(16) char smem[131072];

    const int tid  = threadIdx.x;
    const int lane = tid & 63;
    const int wid  = tid >> 6;
    const int bid  = blockIdx.x;
    const int xcd  = bid & 7;
    const int lj   = bid >> 3;
    const int mt   = lj / NTL;
    const int nt   = lj - mt * NTL;
    const int m0   = (xcd * mpx + mt) * 256;
    const int n0   = nt * 256;       // row offset into concatenated W

    // ---- staging geometry: thread covers segments j0=tid, j1=tid+512 of each
    //      16KB section (row = j>>2 of 256, chunk = j&3 of 4 x 16B)
    const int j0 = tid, j1 = tid + 512;
    const char* gA = (const char*)A;
    const char* gW = (const char*)W;
    const size_t gA0 = (size_t)(m0 + (j0 >> 2)) * (K * 2) + (j0 & 3) * 16;
    const size_t gA1 = (size_t)(m0 + (j1 >> 2)) * (K * 2) + (j1 & 3) * 16;
    const size_t gW0 = (size_t)(n0 + (j0 >> 2)) * (K * 2) + (j0 & 3) * 16;
    const size_t gW1 = (size_t)(n0 + (j1 >> 2)) * (K * 2) + (j1 & 3) * 16;

    auto STAGE_SEC = [&](int bufb, int p, int t) {
        const int ks = p >> 1;
        const int secb = bufb + (p & 1) * 16384 + ks * 32768;
        const size_t kb = (size_t)t * 128 + ks * 64;
        if ((p & 1) == 0) {
            GLD16(gA + gA0 + kb, &smem[secb] + j0 * 16);
            GLD16(gA + gA1 + kb, &smem[secb] + j1 * 16);
        } else {
            GLD16(gW + gW0 + kb, &smem[secb] + j0 * 16);
            GLD16(gW + gW1 + kb, &smem[secb] + j1 * 16);
        }
    };

    // ---- compute geometry
    const int wr = wid >> 2;                  // 0..1 -> 128-row group
    const int wc = wid & 3;                   // 0..3 -> 64-col group
    const int rl = lane & 15;
    const int kc = (lane >> 4) << 4;          // chunk byte within 64B row

    f32x4 acc[8][4];
    #pragma unroll
    for (int i = 0; i < 8; ++i)
        #pragma unroll
        for (int j = 0; j < 4; ++j)
            acc[i][j] = (f32x4){0.f, 0.f, 0.f, 0.f};

    // ---- prologue: stage all 4 sections of K-tile 0 into buf 0, full drain
    #pragma unroll
    for (int p = 0; p < 4; ++p) STAGE_SEC(0, p, 0);
    asm volatile("s_waitcnt vmcnt(0)" ::: "memory");
    __builtin_amdgcn_s_barrier();

    // ---- main loop: 12 K-tiles x 4 phases
    for (int t = 0; t < NT; ++t) {
        const int db  = (t & 1) << 16;        // compute buffer base
        const int nb2 = db ^ 65536;           // staging buffer base
        const char* sb = &smem[db];
        f16x8 breg[4];

        #pragma unroll
        for (int p = 0; p < 4; ++p) {
            const int ks = p >> 1, mh = p & 1;
            const char* asec = sb + ks * 32768;
            const char* bsec = sb + 16384 + ks * 32768;

            f16x8 areg[4];
            #pragma unroll
            for (int mi = 0; mi < 4; ++mi)
                areg[mi] = *(const f16x8*)(asec + (wr * 128 + (mh * 4 + mi) * 16 + rl) * 64 + kc);
            if (mh == 0) {
                #pragma unroll
                for (int nf = 0; nf < 4; ++nf)
                    breg[nf] = *(const f16x8*)(bsec + (wc * 64 + nf * 16 + rl) * 64 + kc);
            }
            if (t + 1 < NT) STAGE_SEC(nb2, p, t + 1);

            __builtin_amdgcn_s_barrier();
            asm volatile("s_waitcnt lgkmcnt(0)" ::: "memory");
            __builtin_amdgcn_sched_barrier(0);
            __builtin_amdgcn_s_setprio(1);
            #pragma unroll
            for (int mi = 0; mi < 4; ++mi)
                #pragma unroll
                for (int nf = 0; nf < 4; ++nf)
                    acc[mh * 4 + mi][nf] = __builtin_amdgcn_mfma_f32_16x16x32_f16(
                        areg[mi], breg[nf], acc[mh * 4 + mi][nf], 0, 0, 0);
            __builtin_amdgcn_s_setprio(0);
            if (t + 1 < NT) asm volatile("s_waitcnt vmcnt(4)" ::: "memory");
            else            asm volatile("s_waitcnt vmcnt(0)" ::: "memory");
            __builtin_amdgcn_s_barrier();
        }
    }

    // ---- epilogue: D frag mapping col=lane&15, row=(lane>>4)*4+r
    const int erow0 = m0 + wr * 128 + ((lane >> 4) << 2);
    if (of32) {
        const int col0 = n0 + wc * 64 + rl;
        #pragma unroll
        for (int mf = 0; mf < 8; ++mf)
            #pragma unroll
            for (int nf = 0; nf < 4; ++nf)
                #pragma unroll
                for (int r = 0; r < 4; ++r)
                    of32[(size_t)(erow0 + mf * 16 + r) * CDIM + (col0 + nf * 16)] =
                        acc[mf][nf][r];
    } else {
        const int mat  = nt / 3;
        const int col0 = (nt - mat * 3) * 256 + wc * 64 + rl;
        _Float16* o = (mat == 0) ? o0 : ((mat == 1) ? o1 : o2);
        if (mat == 2) {
            #pragma unroll
            for (int mf = 0; mf < 8; ++mf)
                #pragma unroll
                for (int nf = 0; nf < 4; ++nf)
                    #pragma unroll
                    for (int r = 0; r < 4; ++r)
                        o[(size_t)(erow0 + mf * 16 + r) * CDIM + (col0 + nf * 16)] =
                            (_Float16)(1.0f / (1.0f + __expf(-acc[mf][nf][r])));
        } else {
            #pragma unroll
            for (int mf = 0; mf < 8; ++mf)
                #pragma unroll
                for (int nf = 0; nf < 4; ++nf)
                    #pragma unroll
                    for (int r = 0; r < 4; ++r)
                        o[(size_t)(erow0 + mf * 16 + r) * CDIM + (col0 + nf * 16)] =
                            (_Float16)acc[mf][nf][r];
        }
    }
}

// ---------------------------------------------------------------------------
// WKV (math verified rounds 2-11); k,v,sr fp16 in memory, f32 in-register.
// ---------------------------------------------------------------------------
#define WKV_STEP(a, bb, p, kt, vt, w)                \
    {                                                \
        const float pn = fmaxf((p) - (w), (kt));     \
        const float e1 = __expf((p) - (w) - pn);     \
        const float e2 = __expf((kt) - pn);          \
        (a)  = e1 * (a)  + e2 * (vt);                \
        (bb) = e1 * (bb) + e2;                       \
        (p)  = pn;                                   \
    }

__global__ __launch_bounds__(256) void wkv_phase1(
    const _Float16* __restrict__ k, const _Float16* __restrict__ v,
    const float* __restrict__ decay,
    float* __restrict__ Sfa, float* __restrict__ Sfb, float* __restrict__ Sfp,
    float* __restrict__ Sba, float* __restrict__ Sbb, float* __restrict__ Sbp) {
    const int c = blockIdx.x * 256 + threadIdx.x;
    const int j = blockIdx.y;
    const int b = blockIdx.z;
    const float w = decay[c] * (1.0f / (float)TLEN);

    const size_t base = ((size_t)b * TLEN + (size_t)j * LCH) * CDIM + c;
    float kt[LCH], vt[LCH];
    #pragma unroll
    for (int i = 0; i < LCH; ++i) {
        kt[i] = (float)k[base + (size_t)i * CDIM];
        vt[i] = (float)v[base + (size_t)i * CDIM];
    }

    const size_t idx = ((size_t)b * NCH + j) * CDIM + c;

    float a = 0.0f, bb = 0.0f, p = -1e38f;
    #pragma unroll
    for (int i = 0; i < LCH; ++i) WKV_STEP(a, bb, p, kt[i], vt[i], w);
    Sfa[idx] = a; Sfb[idx] = bb; Sfp[idx] = p;

    a = 0.0f; bb = 0.0f; p = -1e38f;
    #pragma unroll
    for (int i = LCH - 1; i >= 0; --i) WKV_STEP(a, bb, p, kt[i], vt[i], w);
    Sba[idx] = a; Sbb[idx] = bb; Sbp[idx] = p;
}

#define WKV_COMBINE(a, bb, p, as, bs, ps, wL)        \
    {                                                \
        const float pn = fmaxf((p) - (wL), (ps));    \
        const float e1 = __expf((p) - (wL) - pn);    \
        const float e2 = __expf((ps) - pn);          \
        (a)  = e1 * (a)  + e2 * (as);                \
        (bb) = e1 * (bb) + e2 * (bs);                \
        (p)  = pn;                                   \
    }

// blockIdx.z = direction. Software-pipelined: groups of 4, static dbuf (A/B).
__global__ __launch_bounds__(64) void wkv_phase2(
    const float* __restrict__ Sfa, const float* __restrict__ Sfb, const float* __restrict__ Sfp,
    const float* __restrict__ Sba, const float* __restrict__ Sbb, const float* __restrict__ Sbp,
    const float* __restrict__ decay,
    float* __restrict__ Lina, float* __restrict__ Linb, float* __restrict__ Linp,
    float* __restrict__ Rina, float* __restrict__ Rinb, float* __restrict__ Rinp) {
    const int c = blockIdx.x * 64 + threadIdx.x;
    const int b = blockIdx.y;
    const int dir = blockIdx.z;
    const float wL = decay[c] * ((float)LCH / (float)TLEN);

    const float* Sa = dir ? Sba : Sfa;
    const float* Sb = dir ? Sbb : Sfb;
    const float* Sp = dir ? Sbp : Sfp;
    float* Oa = dir ? Rina : Lina;
    float* Ob = dir ? Rinb : Linb;
    float* Op = dir ? Rinp : Linp;

    const size_t base = (size_t)b * NCH * CDIM + c;
    auto IDX = [&](int j) {
        return base + (size_t)(dir ? (NCH - 1 - j) : j) * CDIM;
    };

    float gaA[4], gbA[4], gpA[4], gaB[4], gbB[4], gpB[4];
    #pragma unroll
    for (int u = 0; u < 4; ++u) {
        const size_t id = IDX(u);
        gaA[u] = Sa[id]; gbA[u] = Sb[id]; gpA[u] = Sp[id];
    }
    float a = 0.0f, bb = 0.0f, p = -1e38f;

    for (int jg = 0; jg < NCH; jg += 8) {
        #pragma unroll
        for (int u = 0; u < 4; ++u) {
            const size_t id = IDX(jg + 4 + u);
            gaB[u] = Sa[id]; gbB[u] = Sb[id]; gpB[u] = Sp[id];
        }
        #pragma unroll
        for (int u = 0; u < 4; ++u) {
            const size_t id = IDX(jg + u);
            Oa[id] = a; Ob[id] = bb; Op[id] = p;
            WKV_COMBINE(a, bb, p, gaA[u], gbA[u], gpA[u], wL);
        }
        if (jg + 8 < NCH) {
            #pragma unroll
            for (int u = 0; u < 4; ++u) {
                const size_t id = IDX(jg + 8 + u);
                gaA[u] = Sa[id]; gbA[u] = Sb[id]; gpA[u] = Sp[id];
            }
        }
        #pragma unroll
        for (int u = 0; u < 4; ++u) {
            const size_t id = IDX(jg + 4 + u);
            Oa[id] = a; Ob[id] = bb; Op[id] = p;
            WKV_COMBINE(a, bb, p, gaB[u], gbB[u], gpB[u], wL);
        }
    }
}

// phase3: combine + fuse z = sr*y; z written fp16 (final GEMM's A).
__global__ __launch_bounds__(256) void wkv_phase3(
    const _Float16* __restrict__ k, const _Float16* __restrict__ v,
    const _Float16* __restrict__ sr,
    const float* __restrict__ Lina, const float* __restrict__ Linb, const float* __restrict__ Linp,
    const float* __restrict__ Rina, const float* __restrict__ Rinb, const float* __restrict__ Rinp,
    const float* __restrict__ decay, const float* __restrict__ first,
    _Float16* __restrict__ zh) {
    const int c = blockIdx.x * 256 + threadIdx.x;
    const int j = blockIdx.y;
    const int b = blockIdx.z;
    const float w = decay[c] * (1.0f / (float)TLEN);
    const float u = first[c] * (1.0f / (float)TLEN);

    const size_t base = ((size_t)b * TLEN + (size_t)j * LCH) * CDIM + c;
    float kt[LCH], vt[LCH];
    #pragma unroll
    for (int i = 0; i < LCH; ++i) {
        kt[i] = (float)k[base + (size_t)i * CDIM];
        vt[i] = (float)v[base + (size_t)i * CDIM];
    }

    const size_t idx = ((size_t)b * NCH + j) * CDIM + c;

    float ar[LCH], br[LCH], pr[LCH];
    {
        float a = Rina[idx], bb = Rinb[idx], p = Rinp[idx];
        #pragma unroll
        for (int i = LCH - 1; i >= 0; --i) {
            ar[i] = a; br[i] = bb; pr[i] = p;
            WKV_STEP(a, bb, p, kt[i], vt[i], w);
        }
    }
    {
        float a = Lina[idx], bb = Linb[idx], p = Linp[idx];
        #pragma unroll
        for (int i = 0; i < LCH; ++i) {
            const size_t off = base + (size_t)i * CDIM;
            const float srt = (float)sr[off];
            const float ps = u + kt[i];
            const float q  = fmaxf(fmaxf(p, pr[i]), ps);
            const float eL = __expf(p - q);
            const float eR = __expf(pr[i] - q);
            const float eS = __expf(ps - q);
            const float num = eL * a  + eR * ar[i] + eS * vt[i];
            const float den = eL * bb + eR * br[i] + eS;
            zh[off] = (_Float16)(srt * (num / den));
            WKV_STEP(a, bb, p, kt[i], vt[i], w);
        }
    }
}

// ---------------------------------------------------------------------------
// Driver. ws: [Wcat 3*WN f16 | Woh WN f16 | 12 state f32 planes | kh vh srh
// xh f16 planes (zh aliases xh)]. Batch-chunked to fit ws_size.
// ---------------------------------------------------------------------------
extern "C" void kernel_launch(void* const* d_in, const int* in_sizes, int n_in,
                              void* d_out, int out_size, void* d_ws, size_t ws_size,
                              hipStream_t stream) {
    const float* x     = (const float*)d_in[0];
    const float* Wk    = (const float*)d_in[1];
    const float* Wv    = (const float*)d_in[2];
    const float* Wr    = (const float*)d_in[3];
    const float* Wo    = (const float*)d_in[4];
    const float* decay = (const float*)d_in[5];
    const float* first = (const float*)d_in[6];
    float* out = (float*)d_out;

    const size_t WN = (size_t)CDIM * CDIM;
    const size_t wbytes = 4 * WN * sizeof(_Float16);
    const size_t per_b  = (size_t)TLEN * CDIM * 8 + 12ull * NCH * CDIM * 4; // 17.3 MB
    if (ws_size < wbytes + per_b) return;
    int nb = (int)((ws_size - wbytes) / per_b);
    if (nb > BSZ) nb = BSZ;

    _Float16* wsp  = (_Float16*)d_ws;
    _Float16* Wcat = wsp;                 // rows 0-767 Wk, 768-1535 Wv, 1536-2303 Wr
    _Float16* Woh  = wsp + 3 * WN;

    const size_t NE = (size_t)nb * TLEN * CDIM;
    const size_t NP = (size_t)nb * NCH * CDIM;
    float* Sfa = (float*)(wsp + 4 * WN);
    float* Sfb = Sfa + NP;  float* Sfp = Sfb + NP;
    float* Sba = Sfp + NP;  float* Sbb = Sba + NP;  float* Sbp = Sbb + NP;
    float* Lina = Sbp + NP; float* Linb = Lina + NP; float* Linp = Linb + NP;
    float* Rina = Linp + NP; float* Rinb = Rina + NP; float* Rinp = Rinb + NP;
    _Float16* kh  = (_Float16*)(Rinp + NP);
    _Float16* vh  = kh + NE;
    _Float16* srh = vh + NE;
    _Float16* xh  = srh + NE;
    _Float16* zh  = xh;   // alias: phase3 runs after the merged input GEMM

    split_f16<<<dim3((int)(WN / 1024)), dim3(256), 0, stream>>>(Wk, Wcat + 0 * WN, (int)(WN / 4));
    split_f16<<<dim3((int)(WN / 1024)), dim3(256), 0, stream>>>(Wv, Wcat + 1 * WN, (int)(WN / 4));
    split_f16<<<dim3((int)(WN / 1024)), dim3(256), 0, stream>>>(Wr, Wcat + 2 * WN, (int)(WN / 4));
    split_f16<<<dim3((int)(WN / 1024)), dim3(256), 0, stream>>>(Wo, Woh, (int)(WN / 4));

    for (int b0 = 0; b0 < BSZ; b0 += nb) {
        const int curb = (BSZ - b0 < nb) ? (BSZ - b0) : nb;
        const int rows = curb * TLEN;
        const float* xc = x   + (size_t)b0 * TLEN * CDIM;
        float*       oc = out + (size_t)b0 * TLEN * CDIM;

        const int n4 = rows * CDIM / 4;
        split_f16<<<dim3(n4 / 256), dim3(256), 0, stream>>>(xc, xh, n4);

        const int mtiles = rows / 256;     // divisible by 8 (= curb*8)
        const int mpx    = mtiles / 8;

        // merged k|v|sr GEMM: Wcat rows 0-2303 -> 9 ntiles of 256
        gemm_8ph<<<dim3(mtiles * 9), dim3(512), 0, stream>>>(
            xh, Wcat, kh, vh, srh, nullptr, mpx, 9);

        wkv_phase1<<<dim3(CDIM / 256, NCH, curb), dim3(256), 0, stream>>>(
            kh, vh, decay, Sfa, Sfb, Sfp, Sba, Sbb, Sbp);
        wkv_phase2<<<dim3(CDIM / 64, curb, 2), dim3(64), 0, stream>>>(
            Sfa, Sfb, Sfp, Sba, Sbb, Sbp, decay,
            Lina, Linb, Linp, Rina, Rinb, Rinp);
        wkv_phase3<<<dim3(CDIM / 256, NCH, curb), dim3(256), 0, stream>>>(
            kh, vh, srh, Lina, Linb, Linp, Rina, Rinb, Rinp, decay, first, zh);

        // Wo GEMM: 3 ntiles of 256, f32 output
        gemm_8ph<<<dim3(mtiles * 3), dim3(512), 0, stream>>>(
            zh, Woh, nullptr, nullptr, nullptr, oc, mpx, 3);
    }
}

// Round 13
// 169.579 us; speedup vs baseline: 1.1282x; 1.1282x over previous
//
#include <hip/hip_runtime.h>

#define BSZ 8
#define TLEN 2048
#define CDIM 768
#define LCH 16
#define NCH (TLEN / LCH)

typedef __attribute__((ext_vector_type(4))) float f32x4;
typedef __attribute__((ext_vector_type(8))) _Float16 f16x8;   // 8 f16 = 4 VGPRs (MFMA operand)
typedef __attribute__((ext_vector_type(4))) _Float16 f16x4;
typedef __attribute__((ext_vector_type(4))) float float4v;

// async global->LDS, 16B per lane; LDS dest = wave-uniform base + lane*16
#define GLD16(g, l)                                                          \
    __builtin_amdgcn_global_load_lds(                                        \
        (const __attribute__((address_space(1))) unsigned int*)(g),          \
        (__attribute__((address_space(3))) unsigned int*)(l), 16, 0, 0)

// ---------------------------------------------------------------------------
// f32 -> f16 cast, 4 elements/thread (x and weight planes)
// ---------------------------------------------------------------------------
__global__ __launch_bounds__(256) void split_f16(const float* __restrict__ src,
                                                 _Float16* __restrict__ dst, int n4) {
    int i = blockIdx.x * 256 + threadIdx.x;
    if (i >= n4) return;
    float4v f = ((const float4v*)src)[i];
    f16x4 h;
    #pragma unroll
    for (int j = 0; j < 4; ++j) h[j] = (_Float16)f[j];
    ((f16x4*)dst)[i] = h;
}

// ---------------------------------------------------------------------------
// m97-structure fp16 GEMM (NT): out[m,n] = sum_k A[m,k]*W[n,k]. K = 768.
// 128x128 tile, BK=64, 256 thr (4 waves, 2x2), wave tile 64x64 (4x4 frags).
// LDS: 2 bufs x (A 16KB + B 16KB) = 64KB -> 2 blocks/CU (cross-block overlap
// of barrier drains -- the m97/m103 lever; 128-tile beat 256-tile there).
// 128B LDS rows; PROVEN 0-conflict swizzle (rounds 9-10 counters): LDS chunk
// c of row r holds global k-group c^(r&7); staging source pre-swizzled with
// gq=(tid&7)^((tid>>3)&7), linear LDS dest; read XORs with rl&7.
// Simple 2-barrier loop: STAGE(t+1) | COMPUTE(t) | __syncthreads (drain).
// W concatenated [NTL*128 x 768]. Merged NTL=18: nt/6 -> kh|vh|srh (sigmoid
// on srh); Wo NTL=6: f32 store to of32.
// Block decode: bid = xcd + 8*(mt*NTL + nt); m0 = (xcd*mpx + mt)*128.
// ---------------------------------------------------------------------------
__global__ __launch_bounds__(256, 2) void gemm_128(
    const _Float16* __restrict__ A, const _Float16* __restrict__ W,
    _Float16* __restrict__ o0, _Float16* __restrict__ o1, _Float16* __restrict__ o2,
    float* __restrict__ of32, int mpx, int NTL) {
    constexpr int K = CDIM;          // 768
    constexpr int NT = K / 64;       // 12 K-tiles of 64 (=128B)
    __shared__ __align__(16) char smem[65536];   // buf b @ b*32768: A @+0, B @+16384

    const int tid  = threadIdx.x;
    const int lane = tid & 63;
    const int wid  = tid >> 6;
    const int bid  = blockIdx.x;
    const int xcd  = bid & 7;
    const int lj   = bid >> 3;
    const int mt   = lj / NTL;
    const int nt   = lj - mt * NTL;
    const int m0   = (xcd * mpx + mt) * 128;
    const int n0   = nt * 128;       // row offset into concatenated W

    // ---- staging: thread covers segs tid+q*256 (q=0..3) of each 16KB tile;
    //      seg j: row j>>3, LDS chunk j&7, global chunk (j&7)^(row&7).
    const int gq = (tid & 7) ^ ((tid >> 3) & 7);   // q-invariant (q*32 = 0 mod 8)
    const char* gA = (const char*)A;
    const char* gW = (const char*)W;
    const size_t gofsA = (size_t)(m0 + (tid >> 3)) * (K * 2) + gq * 16;
    const size_t gofsB = (size_t)(n0 + (tid >> 3)) * (K * 2) + gq * 16;
    const int lofs = tid * 16;

    auto STAGE = [&](int bufb, int t) {
        const size_t kb = (size_t)t * 128;
        #pragma unroll
        for (int q = 0; q < 4; ++q) {              // q: 32-row stripes (=49152B)
            GLD16(gA + gofsA + kb + (size_t)q * 49152, &smem[bufb] + lofs + q * 4096);
            GLD16(gW + gofsB + kb + (size_t)q * 49152, &smem[bufb + 16384] + lofs + q * 4096);
        }
    };

    // ---- compute: wr = wid>>1 (row group), wc = wid&1 (col group)
    const int wr = wid >> 1, wc = wid & 1;
    const int rl = lane & 15;
    const int kc0 = ((((lane >> 4)    ) ^ (rl & 7)) << 4);
    const int kc1 = ((((lane >> 4) + 4) ^ (rl & 7)) << 4);

    f32x4 acc[4][4];
    #pragma unroll
    for (int i = 0; i < 4; ++i)
        #pragma unroll
        for (int j = 0; j < 4; ++j)
            acc[i][j] = (f32x4){0.f, 0.f, 0.f, 0.f};

    auto COMPUTE = [&](int bufb) {
        const char* sa = &smem[bufb];
        const char* sbb = &smem[bufb + 16384];
        #pragma unroll
        for (int ks = 0; ks < 2; ++ks) {
            const int kc = ks ? kc1 : kc0;
            f16x8 a[4], b[4];
            #pragma unroll
            for (int fi = 0; fi < 4; ++fi)
                a[fi] = *(const f16x8*)(sa + (wr * 64 + fi * 16 + rl) * 128 + kc);
            #pragma unroll
            for (int fj = 0; fj < 4; ++fj)
                b[fj] = *(const f16x8*)(sbb + (wc * 64 + fj * 16 + rl) * 128 + kc);
            #pragma unroll
            for (int fi = 0; fi < 4; ++fi)
                #pragma unroll
                for (int fj = 0; fj < 4; ++fj)
                    acc[fi][fj] = __builtin_amdgcn_mfma_f32_16x16x32_f16(
                        a[fi], b[fj], acc[fi][fj], 0, 0, 0);
        }
    };

    // ---- m97 2-barrier loop
    STAGE(0, 0);
    __syncthreads();
    int buf = 0;
    for (int t = 0; t < NT; ++t) {
        if (t + 1 < NT) STAGE(buf ^ 32768, t + 1);
        COMPUTE(buf);
        __syncthreads();
        buf ^= 32768;
    }

    // ---- epilogue: D frag mapping col=lane&15, row=(lane>>4)*4+r
    const int erow0 = m0 + wr * 64 + ((lane >> 4) << 2);
    if (of32) {
        const int col0 = n0 + wc * 64 + rl;
        #pragma unroll
        for (int mf = 0; mf < 4; ++mf)
            #pragma unroll
            for (int nf = 0; nf < 4; ++nf)
                #pragma unroll
                for (int r = 0; r < 4; ++r)
                    of32[(size_t)(erow0 + mf * 16 + r) * CDIM + (col0 + nf * 16)] =
                        acc[mf][nf][r];
    } else {
        const int mat  = nt / 6;
        const int col0 = (nt - mat * 6) * 128 + wc * 64 + rl;
        _Float16* o = (mat == 0) ? o0 : ((mat == 1) ? o1 : o2);
        if (mat == 2) {
            #pragma unroll
            for (int mf = 0; mf < 4; ++mf)
                #pragma unroll
                for (int nf = 0; nf < 4; ++nf)
                    #pragma unroll
                    for (int r = 0; r < 4; ++r)
                        o[(size_t)(erow0 + mf * 16 + r) * CDIM + (col0 + nf * 16)] =
                            (_Float16)(1.0f / (1.0f + __expf(-acc[mf][nf][r])));
        } else {
            #pragma unroll
            for (int mf = 0; mf < 4; ++mf)
                #pragma unroll
                for (int nf = 0; nf < 4; ++nf)
                    #pragma unroll
                    for (int r = 0; r < 4; ++r)
                        o[(size_t)(erow0 + mf * 16 + r) * CDIM + (col0 + nf * 16)] =
                            (_Float16)acc[mf][nf][r];
        }
    }
}

// ---------------------------------------------------------------------------
// WKV (math verified rounds 2-12); k,v,sr fp16 in memory, f32 in-register.
// ---------------------------------------------------------------------------
#define WKV_STEP(a, bb, p, kt, vt, w)                \
    {                                                \
        const float pn = fmaxf((p) - (w), (kt));     \
        const float e1 = __expf((p) - (w) - pn);     \
        const float e2 = __expf((kt) - pn);          \
        (a)  = e1 * (a)  + e2 * (vt);                \
        (bb) = e1 * (bb) + e2;                       \
        (p)  = pn;                                   \
    }

__global__ __launch_bounds__(256) void wkv_phase1(
    const _Float16* __restrict__ k, const _Float16* __restrict__ v,
    const float* __restrict__ decay,
    float* __restrict__ Sfa, float* __restrict__ Sfb, float* __restrict__ Sfp,
    float* __restrict__ Sba, float* __restrict__ Sbb, float* __restrict__ Sbp) {
    const int c = blockIdx.x * 256 + threadIdx.x;
    const int j = blockIdx.y;
    const int b = blockIdx.z;
    const float w = decay[c] * (1.0f / (float)TLEN);

    const size_t base = ((size_t)b * TLEN + (size_t)j * LCH) * CDIM + c;
    float kt[LCH], vt[LCH];
    #pragma unroll
    for (int i = 0; i < LCH; ++i) {
        kt[i] = (float)k[base + (size_t)i * CDIM];
        vt[i] = (float)v[base + (size_t)i * CDIM];
    }

    const size_t idx = ((size_t)b * NCH + j) * CDIM + c;

    float a = 0.0f, bb = 0.0f, p = -1e38f;
    #pragma unroll
    for (int i = 0; i < LCH; ++i) WKV_STEP(a, bb, p, kt[i], vt[i], w);
    Sfa[idx] = a; Sfb[idx] = bb; Sfp[idx] = p;

    a = 0.0f; bb = 0.0f; p = -1e38f;
    #pragma unroll
    for (int i = LCH - 1; i >= 0; --i) WKV_STEP(a, bb, p, kt[i], vt[i], w);
    Sba[idx] = a; Sbb[idx] = bb; Sbp[idx] = p;
}

#define WKV_COMBINE(a, bb, p, as, bs, ps, wL)        \
    {                                                \
        const float pn = fmaxf((p) - (wL), (ps));    \
        const float e1 = __expf((p) - (wL) - pn);    \
        const float e2 = __expf((ps) - pn);          \
        (a)  = e1 * (a)  + e2 * (as);                \
        (bb) = e1 * (bb) + e2 * (bs);                \
        (p)  = pn;                                   \
    }

// blockIdx.z = direction. Software-pipelined: groups of 4, static dbuf (A/B).
__global__ __launch_bounds__(64) void wkv_phase2(
    const float* __restrict__ Sfa, const float* __restrict__ Sfb, const float* __restrict__ Sfp,
    const float* __restrict__ Sba, const float* __restrict__ Sbb, const float* __restrict__ Sbp,
    const float* __restrict__ decay,
    float* __restrict__ Lina, float* __restrict__ Linb, float* __restrict__ Linp,
    float* __restrict__ Rina, float* __restrict__ Rinb, float* __restrict__ Rinp) {
    const int c = blockIdx.x * 64 + threadIdx.x;
    const int b = blockIdx.y;
    const int dir = blockIdx.z;
    const float wL = decay[c] * ((float)LCH / (float)TLEN);

    const float* Sa = dir ? Sba : Sfa;
    const float* Sb = dir ? Sbb : Sfb;
    const float* Sp = dir ? Sbp : Sfp;
    float* Oa = dir ? Rina : Lina;
    float* Ob = dir ? Rinb : Linb;
    float* Op = dir ? Rinp : Linp;

    const size_t base = (size_t)b * NCH * CDIM + c;
    auto IDX = [&](int j) {
        return base + (size_t)(dir ? (NCH - 1 - j) : j) * CDIM;
    };

    float gaA[4], gbA[4], gpA[4], gaB[4], gbB[4], gpB[4];
    #pragma unroll
    for (int u = 0; u < 4; ++u) {
        const size_t id = IDX(u);
        gaA[u] = Sa[id]; gbA[u] = Sb[id]; gpA[u] = Sp[id];
    }
    float a = 0.0f, bb = 0.0f, p = -1e38f;

    for (int jg = 0; jg < NCH; jg += 8) {
        #pragma unroll
        for (int u = 0; u < 4; ++u) {
            const size_t id = IDX(jg + 4 + u);
            gaB[u] = Sa[id]; gbB[u] = Sb[id]; gpB[u] = Sp[id];
        }
        #pragma unroll
        for (int u = 0; u < 4; ++u) {
            const size_t id = IDX(jg + u);
            Oa[id] = a; Ob[id] = bb; Op[id] = p;
            WKV_COMBINE(a, bb, p, gaA[u], gbA[u], gpA[u], wL);
        }
        if (jg + 8 < NCH) {
            #pragma unroll
            for (int u = 0; u < 4; ++u) {
                const size_t id = IDX(jg + 8 + u);
                gaA[u] = Sa[id]; gbA[u] = Sb[id]; gpA[u] = Sp[id];
            }
        }
        #pragma unroll
        for (int u = 0; u < 4; ++u) {
            const size_t id = IDX(jg + 4 + u);
            Oa[id] = a; Ob[id] = bb; Op[id] = p;
            WKV_COMBINE(a, bb, p, gaB[u], gbB[u], gpB[u], wL);
        }
    }
}

// phase3: combine + fuse z = sr*y; z written fp16 (final GEMM's A).
__global__ __launch_bounds__(256) void wkv_phase3(
    const _Float16* __restrict__ k, const _Float16* __restrict__ v,
    const _Float16* __restrict__ sr,
    const float* __restrict__ Lina, const float* __restrict__ Linb, const float* __restrict__ Linp,
    const float* __restrict__ Rina, const float* __restrict__ Rinb, const float* __restrict__ Rinp,
    const float* __restrict__ decay, const float* __restrict__ first,
    _Float16* __restrict__ zh) {
    const int c = blockIdx.x * 256 + threadIdx.x;
    const int j = blockIdx.y;
    const int b = blockIdx.z;
    const float w = decay[c] * (1.0f / (float)TLEN);
    const float u = first[c] * (1.0f / (float)TLEN);

    const size_t base = ((size_t)b * TLEN + (size_t)j * LCH) * CDIM + c;
    float kt[LCH], vt[LCH];
    #pragma unroll
    for (int i = 0; i < LCH; ++i) {
        kt[i] = (float)k[base + (size_t)i * CDIM];
        vt[i] = (float)v[base + (size_t)i * CDIM];
    }

    const size_t idx = ((size_t)b * NCH + j) * CDIM + c;

    float ar[LCH], br[LCH], pr[LCH];
    {
        float a = Rina[idx], bb = Rinb[idx], p = Rinp[idx];
        #pragma unroll
        for (int i = LCH - 1; i >= 0; --i) {
            ar[i] = a; br[i] = bb; pr[i] = p;
            WKV_STEP(a, bb, p, kt[i], vt[i], w);
        }
    }
    {
        float a = Lina[idx], bb = Linb[idx], p = Linp[idx];
        #pragma unroll
        for (int i = 0; i < LCH; ++i) {
            const size_t off = base + (size_t)i * CDIM;
            const float srt = (float)sr[off];
            const float ps = u + kt[i];
            const float q  = fmaxf(fmaxf(p, pr[i]), ps);
            const float eL = __expf(p - q);
            const float eR = __expf(pr[i] - q);
            const float eS = __expf(ps - q);
            const float num = eL * a  + eR * ar[i] + eS * vt[i];
            const float den = eL * bb + eR * br[i] + eS;
            zh[off] = (_Float16)(srt * (num / den));
            WKV_STEP(a, bb, p, kt[i], vt[i], w);
        }
    }
}

// ---------------------------------------------------------------------------
// Driver. ws: [Wcat 3*WN f16 | Woh WN f16 | 12 state f32 planes | kh vh srh
// xh f16 planes (zh aliases xh)]. Batch-chunked to fit ws_size.
// ---------------------------------------------------------------------------
extern "C" void kernel_launch(void* const* d_in, const int* in_sizes, int n_in,
                              void* d_out, int out_size, void* d_ws, size_t ws_size,
                              hipStream_t stream) {
    const float* x     = (const float*)d_in[0];
    const float* Wk    = (const float*)d_in[1];
    const float* Wv    = (const float*)d_in[2];
    const float* Wr    = (const float*)d_in[3];
    const float* Wo    = (const float*)d_in[4];
    const float* decay = (const float*)d_in[5];
    const float* first = (const float*)d_in[6];
    float* out = (float*)d_out;

    const size_t WN = (size_t)CDIM * CDIM;
    const size_t wbytes = 4 * WN * sizeof(_Float16);
    const size_t per_b  = (size_t)TLEN * CDIM * 8 + 12ull * NCH * CDIM * 4; // 17.3 MB
    if (ws_size < wbytes + per_b) return;
    int nb = (int)((ws_size - wbytes) / per_b);
    if (nb > BSZ) nb = BSZ;

    _Float16* wsp  = (_Float16*)d_ws;
    _Float16* Wcat = wsp;                 // rows 0-767 Wk, 768-1535 Wv, 1536-2303 Wr
    _Float16* Woh  = wsp + 3 * WN;

    const size_t NE = (size_t)nb * TLEN * CDIM;
    const size_t NP = (size_t)nb * NCH * CDIM;
    float* Sfa = (float*)(wsp + 4 * WN);
    float* Sfb = Sfa + NP;  float* Sfp = Sfb + NP;
    float* Sba = Sfp + NP;  float* Sbb = Sba + NP;  float* Sbp = Sbb + NP;
    float* Lina = Sbp + NP; float* Linb = Lina + NP; float* Linp = Linb + NP;
    float* Rina = Linp + NP; float* Rinb = Rina + NP; float* Rinp = Rinb + NP;
    _Float16* kh  = (_Float16*)(Rinp + NP);
    _Float16* vh  = kh + NE;
    _Float16* srh = vh + NE;
    _Float16* xh  = srh + NE;
    _Float16* zh  = xh;   // alias: phase3 runs after the merged input GEMM

    split_f16<<<dim3((int)(WN / 1024)), dim3(256), 0, stream>>>(Wk, Wcat + 0 * WN, (int)(WN / 4));
    split_f16<<<dim3((int)(WN / 1024)), dim3(256), 0, stream>>>(Wv, Wcat + 1 * WN, (int)(WN / 4));
    split_f16<<<dim3((int)(WN / 1024)), dim3(256), 0, stream>>>(Wr, Wcat + 2 * WN, (int)(WN / 4));
    split_f16<<<dim3((int)(WN / 1024)), dim3(256), 0, stream>>>(Wo, Woh, (int)(WN / 4));

    for (int b0 = 0; b0 < BSZ; b0 += nb) {
        const int curb = (BSZ - b0 < nb) ? (BSZ - b0) : nb;
        const int rows = curb * TLEN;
        const float* xc = x   + (size_t)b0 * TLEN * CDIM;
        float*       oc = out + (size_t)b0 * TLEN * CDIM;

        const int n4 = rows * CDIM / 4;
        split_f16<<<dim3(n4 / 256), dim3(256), 0, stream>>>(xc, xh, n4);

        const int mtiles = rows / 128;     // divisible by 8
        const int mpx    = mtiles / 8;

        // merged k|v|sr GEMM: Wcat 2304 rows -> 18 ntiles of 128
        gemm_128<<<dim3(mtiles * 18), dim3(256), 0, stream>>>(
            xh, Wcat, kh, vh, srh, nullptr, mpx, 18);

        wkv_phase1<<<dim3(CDIM / 256, NCH, curb), dim3(256), 0, stream>>>(
            kh, vh, decay, Sfa, Sfb, Sfp, Sba, Sbb, Sbp);
        wkv_phase2<<<dim3(CDIM / 64, curb, 2), dim3(64), 0, stream>>>(
            Sfa, Sfb, Sfp, Sba, Sbb, Sbp, decay,
            Lina, Linb, Linp, Rina, Rinb, Rinp);
        wkv_phase3<<<dim3(CDIM / 256, NCH, curb), dim3(256), 0, stream>>>(
            kh, vh, srh, Lina, Linb, Linp, Rina, Rinb, Rinp, decay, first, zh);

        // Wo GEMM: 6 ntiles of 128, f32 output
        gemm_128<<<dim3(mtiles * 6), dim3(256), 0, stream>>>(
            zh, Woh, nullptr, nullptr, nullptr, oc, mpx, 6);
    }
}